// Round 4
// baseline (354.253 us; speedup 1.0000x reference)
//
#include <hip/hip_runtime.h>
#include <hip/hip_bf16.h>

typedef unsigned short ushort_t;
typedef __attribute__((ext_vector_type(8))) short bf16x8;
typedef __attribute__((ext_vector_type(4))) float f32x4;

#define B_SZ 4096
#define N_SZ 8
#define D_SZ 256
#define FF_SZ 2048
#define M_SZ (B_SZ * N_SZ)   // 32768
#define WELEM (D_SZ * D_SZ * N_SZ)  // 524288

__device__ inline float b2f(ushort_t u) {
    union { unsigned int i; float f; } t; t.i = ((unsigned int)u) << 16; return t.f;
}
__device__ inline ushort_t f2b(float f) {
    union { unsigned int i; float f; } t; t.f = f;
    unsigned int i = t.i;
    unsigned int r = (i + 0x7fffu + ((i >> 16) & 1u)) >> 16;
    return (ushort_t)r;
}

// async global->LDS, 16B per lane; LDS dest must be wave-uniform base + lane*16
__device__ inline void gl2lds16(const ushort_t* g, ushort_t* l) {
    __builtin_amdgcn_global_load_lds((const __attribute__((address_space(1))) void*)g,
                                     (__attribute__((address_space(3))) void*)l, 16, 0, 0);
}

// Counted-vmcnt pipeline primitives (T3/T4). Raw barriers do NOT drain counters;
// the explicit counted s_waitcnt is what lets 3 K-tiles of global_load_lds stay
// in flight across barriers (m218: counted-vs-drain0 = +38..73%).
#define BAR()      __builtin_amdgcn_s_barrier()
#define WAITV(n)   asm volatile("s_waitcnt vmcnt(" #n ")" ::: "memory")

// ---------------- convert/repack all weights f32 -> bf16 (unchanged, proven)
__global__ __launch_bounds__(256) void convert_weights(const float* __restrict__ w_in,
                                                       const float* __restrict__ w_out,
                                                       const float* __restrict__ W1,
                                                       const float* __restrict__ W2,
                                                       ushort_t* __restrict__ bt_in,
                                                       ushort_t* __restrict__ bt_out,
                                                       ushort_t* __restrict__ W1b,
                                                       ushort_t* __restrict__ W2b) {
    __shared__ float tile[64][65];
    const int bid = blockIdx.x;
    const int t = threadIdx.x;
    if (bid < 256) {
        const float* w = (bid < 128) ? w_in : w_out;
        ushort_t* bt = (bid < 128) ? bt_in : bt_out;
        const int id = bid & 127;
        const int d10 = (id >> 5) * 64;
        const int j0  = (id & 31) * 64;
#pragma unroll
        for (int it = 0; it < 16; ++it) {
            const int d1l = it * 4 + (t >> 6);
            const int jl = t & 63;
            tile[d1l][jl] = w[(size_t)(d10 + d1l) * 2048 + j0 + jl];
        }
        __syncthreads();
#pragma unroll
        for (int it = 0; it < 16; ++it) {
            const int jl = it * 4 + (t >> 6);
            const int d1l = t & 63;
            const int j = j0 + jl;
            bt[(size_t)(j >> 3) * 2048 + (j & 7) * 256 + d10 + d1l] = f2b(tile[d1l][jl]);
        }
    } else {
        const int id = bid - 256;
        const float* w = (id < 256) ? W1 : W2;
        ushort_t* o = (id < 256) ? W1b : W2b;
        const size_t base = (size_t)(id & 255) * 2048 + t * 8;
        const float4 a = *(const float4*)&w[base];
        const float4 b = *(const float4*)&w[base + 4];
        *(ushort4*)&o[base]     = make_ushort4(f2b(a.x), f2b(a.y), f2b(a.z), f2b(a.w));
        *(ushort4*)&o[base + 4] = make_ushort4(f2b(b.x), f2b(b.y), f2b(b.z), f2b(b.w));
    }
}

// ---------------- LN1: one WAVE per row of 256 (unchanged, proven)
__global__ __launch_bounds__(256) void ln_fast(const float* __restrict__ xin,
                                               const float* __restrict__ gam,
                                               const float* __restrict__ bet,
                                               ushort_t* __restrict__ out) {
    const int wave = threadIdx.x >> 6;
    const int lane = threadIdx.x & 63;
    const size_t row = (size_t)blockIdx.x * 4 + wave;
    const float4 v = *(const float4*)&xin[row * 256 + lane * 4];
    float s = v.x + v.y + v.z + v.w;
    float q = v.x * v.x + v.y * v.y + v.z * v.z + v.w * v.w;
#pragma unroll
    for (int off = 1; off < 64; off <<= 1) {
        s += __shfl_xor(s, off, 64);
        q += __shfl_xor(q, off, 64);
    }
    const float mu = s * (1.0f / 256.0f);
    const float var = q * (1.0f / 256.0f) - mu * mu;
    const float rs = rsqrtf(var + 1e-5f);
    const float4 g = *(const float4*)&gam[lane * 4];
    const float4 b = *(const float4*)&bet[lane * 4];
    ushort4 o;
    o.x = f2b((v.x - mu) * rs * g.x + b.x);
    o.y = f2b((v.y - mu) * rs * g.y + b.y);
    o.z = f2b((v.z - mu) * rs * g.z + b.z);
    o.w = f2b((v.w - mu) * rs * g.w + b.w);
    *(ushort4*)&out[row * 256 + lane * 4] = o;
}

// ============================================================================
// R13 GEMM template: 256x256 tile, BK=32, 8 waves (2x4), per-wave 128x64
// (R12-verified fragment geometry, 0 bank conflicts), 4-buffer counted-vmcnt
// pipeline (loads 3 K-tiles deep across raw barriers).
//
// Pipeline invariants (audited):
//  - stage(kt) DMA retired before B2(kt): in-order vmcnt accounting, each wave
//    waits vmcnt(12)=3 tiles x 4 loads -> its stage(kt) loads are done; B2 makes
//    that true for ALL waves before any ds_read of buf[kt%4].
//  - compute(kt) ds_reads retired before B1(kt+1): every ds_read feeds an MFMA
//    (compiler lgkm waits), so reads are drained when the wave reaches B1.
//  - stage(kt+4) (overwrites buf[kt%4]) issues only after B1(kt+1).
// LDS swizzle: slot ^= (row&3), applied to the GLOBAL source of global_load_lds
// and to the ds_read slot (same involution, rule "both-sides-or-neither").
// 16-lane fragment reads then hit 8 distinct 16B bank slots = 2-way = free.
// ============================================================================

#define WAITV_SCHED(kt, NT) \
    do { if ((kt) + 3 < (NT)) { stage((kt) + 3); WAITV(12); } \
         else if ((kt) + 2 < (NT)) WAITV(8); \
         else if ((kt) + 1 < (NT)) WAITV(4); \
         else WAITV(0); } while (0)

// ---------------- TT gemm, K-split 2-way -> f32 partials (grid 256)
__global__ __launch_bounds__(512, 2) void tt_ks(const ushort_t* __restrict__ A,
                                                const ushort_t* __restrict__ Bt0,
                                                const ushort_t* __restrict__ Bt1,
                                                float* __restrict__ P) {
    __shared__ __attribute__((aligned(16))) ushort_t As[4][256 * 32];   // 64 KB
    __shared__ __attribute__((aligned(16))) ushort_t Bs[4][256 * 32];   // 64 KB

    const int t = threadIdx.x;
    const int mtile = blockIdx.x & 127;
    const int kh = blockIdx.x >> 7;          // K half: 0 or 1
    const int m0 = mtile * 256;
    const int k0 = kh * 1024;
    const int lane = t & 63, wave = t >> 6;
    const int wr = wave >> 2, wc = wave & 3; // 2x4 wave grid, per-wave 128x64
    const int l16 = lane & 15, quad = lane >> 4;
    const int r  = t >> 2;                   // 0..127 staging row (per 128-half)
    const int ssl = (t & 3) ^ (r & 3);       // swizzled source 16B slot

    const ushort_t* Bt = (m0 >= M_SZ / 2) ? Bt1 : Bt0;
    float* Pk = P + (size_t)kh * M_SZ * 256;

    f32x4 acc[8][4];
#pragma unroll
    for (int i = 0; i < 8; i++)
#pragma unroll
        for (int j = 0; j < 4; j++) acc[i][j] = (f32x4)(0.0f);

    auto stage = [&](int kt) {
        const int q = kt & 3;
        const int kg = k0 + kt * 32;         // global K index of this tile
        const int s8 = kg >> 8;              // circulant shift (uniform in tile)
        const int kc = (kg & 255) + ssl * 8; // A col within 256 (swizzled slot)
#pragma unroll
        for (int p = 0; p < 2; ++p) {
            const int mrow = m0 + p * 128 + r;
            const ushort_t* gA = A + (size_t)((mrow & ~7) + (((mrow & 7) - s8) & 7)) * 256 + kc;
            gl2lds16(gA, &As[q][p * 4096 + t * 8]);
        }
#pragma unroll
        for (int p = 0; p < 2; ++p) {
            gl2lds16(Bt + (size_t)(p * 128 + r) * 2048 + kg + ssl * 8, &Bs[q][p * 4096 + t * 8]);
        }
    };

    stage(0); stage(1); stage(2);
    const int aoff = ((quad ^ (l16 & 3)) << 3);  // swizzled read slot (row&3 == l16&3)
#pragma unroll 1
    for (int kt = 0; kt < 32; ++kt) {
        BAR();                                   // all waves done reading buf[(kt+3)%4]
        WAITV_SCHED(kt, 32);                     // issue stage(kt+3); own stage(kt) landed
        BAR();                                   // every wave's stage(kt) landed
        const ushort_t* a = As[kt & 3];
        const ushort_t* b = Bs[kt & 3];
        bf16x8 af[8], bfv[4];
#pragma unroll
        for (int i = 0; i < 8; i++) af[i]  = *(const bf16x8*)&a[(wr * 128 + i * 16 + l16) * 32 + aoff];
#pragma unroll
        for (int j = 0; j < 4; j++) bfv[j] = *(const bf16x8*)&b[(wc * 64 + j * 16 + l16) * 32 + aoff];
        __builtin_amdgcn_s_setprio(1);
#pragma unroll
        for (int i = 0; i < 8; i++)
#pragma unroll
            for (int j = 0; j < 4; j++)
                acc[i][j] = __builtin_amdgcn_mfma_f32_16x16x32_bf16(af[i], bfv[j], acc[i][j], 0, 0, 0);
        __builtin_amdgcn_s_setprio(0);
    }

    // epilogue: raw f32 partial
#pragma unroll
    for (int j = 0; j < 4; j++) {
        const int coln = wc * 64 + j * 16 + l16;
#pragma unroll
        for (int i = 0; i < 8; i++) {
            const int rbase = m0 + wr * 128 + i * 16 + quad * 4;
#pragma unroll
            for (int rr = 0; rr < 4; rr++)
                Pk[(size_t)(rbase + rr) * 256 + coln] = acc[i][j][rr];
        }
    }
}

// ---------------- combine: x = P0+P1+ent; LN2 -> yn; xb = bf16(x)  (grid 8192)
__global__ __launch_bounds__(256) void tt_combine(const float* __restrict__ P,
                                                  const float* __restrict__ ent,
                                                  const float* __restrict__ g2,
                                                  const float* __restrict__ be2,
                                                  ushort_t* __restrict__ yn,
                                                  ushort_t* __restrict__ xb) {
    const int wave = threadIdx.x >> 6;
    const int lane = threadIdx.x & 63;
    const size_t row = (size_t)blockIdx.x * 4 + wave;
    const size_t o = row * 256 + lane * 4;
    const float4 a = *(const float4*)&P[o];
    const float4 b = *(const float4*)&P[(size_t)M_SZ * 256 + o];
    const float4 e = *(const float4*)&ent[o];
    float4 v;
    v.x = a.x + b.x + e.x; v.y = a.y + b.y + e.y;
    v.z = a.z + b.z + e.z; v.w = a.w + b.w + e.w;
    float s = v.x + v.y + v.z + v.w;
    float q = v.x * v.x + v.y * v.y + v.z * v.z + v.w * v.w;
#pragma unroll
    for (int off = 1; off < 64; off <<= 1) {
        s += __shfl_xor(s, off, 64);
        q += __shfl_xor(q, off, 64);
    }
    const float mu = s * (1.0f / 256.0f);
    const float var = q * (1.0f / 256.0f) - mu * mu;
    const float rs = rsqrtf(var + 1e-5f);
    const float4 g = *(const float4*)&g2[lane * 4];
    const float4 be = *(const float4*)&be2[lane * 4];
    ushort4 yo, xo;
    yo.x = f2b((v.x - mu) * rs * g.x + be.x); xo.x = f2b(v.x);
    yo.y = f2b((v.y - mu) * rs * g.y + be.y); xo.y = f2b(v.y);
    yo.z = f2b((v.z - mu) * rs * g.z + be.z); xo.z = f2b(v.z);
    yo.w = f2b((v.w - mu) * rs * g.w + be.w); xo.w = f2b(v.w);
    *(ushort4*)&yn[o] = yo;
    *(ushort4*)&xb[o] = xo;
}

// ---------------- FF GEMM1: H = relu(yn @ W1^T + b1), bf16 (grid 1024)
__global__ __launch_bounds__(512, 2) void ff_g1(const ushort_t* __restrict__ yn,
                                                const ushort_t* __restrict__ W1b,
                                                const float* __restrict__ bias1,
                                                ushort_t* __restrict__ H) {
    __shared__ __attribute__((aligned(16))) ushort_t As[4][256 * 32];
    __shared__ __attribute__((aligned(16))) ushort_t Bs[4][256 * 32];

    const int t = threadIdx.x;
    const int ntile = blockIdx.x >> 7;       // 0..7 (concurrent blocks share W1 panel)
    const int mtile = blockIdx.x & 127;
    const int m0 = mtile * 256;
    const int n0 = ntile * 256;
    const int lane = t & 63, wave = t >> 6;
    const int wr = wave >> 2, wc = wave & 3;
    const int l16 = lane & 15, quad = lane >> 4;
    const int r  = t >> 2;
    const int ssl = (t & 3) ^ (r & 3);

    f32x4 acc[8][4];
#pragma unroll
    for (int i = 0; i < 8; i++)
#pragma unroll
        for (int j = 0; j < 4; j++) acc[i][j] = (f32x4)(0.0f);

    auto stage = [&](int kt) {
        const int q = kt & 3;
        const int kg = kt * 32 + ssl * 8;
#pragma unroll
        for (int p = 0; p < 2; ++p)
            gl2lds16(yn + (size_t)(m0 + p * 128 + r) * 256 + kg, &As[q][p * 4096 + t * 8]);
#pragma unroll
        for (int p = 0; p < 2; ++p)
            gl2lds16(W1b + (size_t)(n0 + p * 128 + r) * 256 + kg, &Bs[q][p * 4096 + t * 8]);
    };

    stage(0); stage(1); stage(2);
    const int aoff = ((quad ^ (l16 & 3)) << 3);
#pragma unroll 1
    for (int kt = 0; kt < 8; ++kt) {
        BAR();
        WAITV_SCHED(kt, 8);
        BAR();
        const ushort_t* a = As[kt & 3];
        const ushort_t* b = Bs[kt & 3];
        bf16x8 af[8], bfv[4];
#pragma unroll
        for (int i = 0; i < 8; i++) af[i]  = *(const bf16x8*)&a[(wr * 128 + i * 16 + l16) * 32 + aoff];
#pragma unroll
        for (int j = 0; j < 4; j++) bfv[j] = *(const bf16x8*)&b[(wc * 64 + j * 16 + l16) * 32 + aoff];
        __builtin_amdgcn_s_setprio(1);
#pragma unroll
        for (int i = 0; i < 8; i++)
#pragma unroll
            for (int j = 0; j < 4; j++)
                acc[i][j] = __builtin_amdgcn_mfma_f32_16x16x32_bf16(af[i], bfv[j], acc[i][j], 0, 0, 0);
        __builtin_amdgcn_s_setprio(0);
    }

    // epilogue: + bias1, relu -> H bf16
#pragma unroll
    for (int j = 0; j < 4; j++) {
        const int col = n0 + wc * 64 + j * 16 + l16;
        const float bb = bias1[col];
#pragma unroll
        for (int i = 0; i < 8; i++) {
            const int rbase = m0 + wr * 128 + i * 16 + quad * 4;
#pragma unroll
            for (int rr = 0; rr < 4; rr++) {
                float v = acc[i][j][rr] + bb;
                v = v > 0.0f ? v : 0.0f;
                H[(size_t)(rbase + rr) * 2048 + col] = f2b(v);
            }
        }
    }
}

// ---------------- FF GEMM2: out = xb + b2 + H @ W2^T (grid 128, K=2048)
__global__ __launch_bounds__(512, 2) void ff_g2(const ushort_t* __restrict__ H,
                                                const ushort_t* __restrict__ W2b,
                                                const float* __restrict__ bias2,
                                                const ushort_t* __restrict__ xb,
                                                float* __restrict__ out) {
    __shared__ __attribute__((aligned(16))) ushort_t As[4][256 * 32];
    __shared__ __attribute__((aligned(16))) ushort_t Bs[4][256 * 32];

    const int t = threadIdx.x;
    const int m0 = blockIdx.x * 256;
    const int lane = t & 63, wave = t >> 6;
    const int wr = wave >> 2, wc = wave & 3;
    const int l16 = lane & 15, quad = lane >> 4;
    const int r  = t >> 2;
    const int ssl = (t & 3) ^ (r & 3);

    f32x4 acc[8][4];
#pragma unroll
    for (int i = 0; i < 8; i++)
#pragma unroll
        for (int j = 0; j < 4; j++) acc[i][j] = (f32x4)(0.0f);

    auto stage = [&](int kt) {
        const int q = kt & 3;
        const int kg = kt * 32 + ssl * 8;
#pragma unroll
        for (int p = 0; p < 2; ++p)
            gl2lds16(H + (size_t)(m0 + p * 128 + r) * 2048 + kg, &As[q][p * 4096 + t * 8]);
#pragma unroll
        for (int p = 0; p < 2; ++p)
            gl2lds16(W2b + (size_t)(p * 128 + r) * 2048 + kg, &Bs[q][p * 4096 + t * 8]);
    };

    stage(0); stage(1); stage(2);
    const int aoff = ((quad ^ (l16 & 3)) << 3);
#pragma unroll 1
    for (int kt = 0; kt < 64; ++kt) {
        BAR();
        WAITV_SCHED(kt, 64);
        BAR();
        const ushort_t* a = As[kt & 3];
        const ushort_t* b = Bs[kt & 3];
        bf16x8 af[8], bfv[4];
#pragma unroll
        for (int i = 0; i < 8; i++) af[i]  = *(const bf16x8*)&a[(wr * 128 + i * 16 + l16) * 32 + aoff];
#pragma unroll
        for (int j = 0; j < 4; j++) bfv[j] = *(const bf16x8*)&b[(wc * 64 + j * 16 + l16) * 32 + aoff];
        __builtin_amdgcn_s_setprio(1);
#pragma unroll
        for (int i = 0; i < 8; i++)
#pragma unroll
            for (int j = 0; j < 4; j++)
                acc[i][j] = __builtin_amdgcn_mfma_f32_16x16x32_bf16(af[i], bfv[j], acc[i][j], 0, 0, 0);
        __builtin_amdgcn_s_setprio(0);
    }

    // epilogue: + bias2 + xb residual -> out (f32)
#pragma unroll
    for (int j = 0; j < 4; j++) {
        const int col = wc * 64 + j * 16 + l16;
        const float b2 = bias2[col];
#pragma unroll
        for (int i = 0; i < 8; i++) {
            const int rbase = m0 + wr * 128 + i * 16 + quad * 4;
#pragma unroll
            for (int rr = 0; rr < 4; rr++) {
                const size_t o = (size_t)(rbase + rr) * 256 + col;
                out[o] = acc[i][j][rr] + b2 + b2f(xb[o]);
            }
        }
    }
}

extern "C" void kernel_launch(void* const* d_in, const int* in_sizes, int n_in,
                              void* d_out, int out_size, void* d_ws, size_t ws_size,
                              hipStream_t stream) {
    const float* ent   = (const float*)d_in[0];
    const float* w_in  = (const float*)d_in[1];
    const float* w_out = (const float*)d_in[2];
    const float* W1    = (const float*)d_in[3];
    const float* bias1 = (const float*)d_in[4];
    const float* W2    = (const float*)d_in[5];
    const float* bias2 = (const float*)d_in[6];
    const float* g1    = (const float*)d_in[7];
    const float* be1   = (const float*)d_in[8];
    const float* g2    = (const float*)d_in[9];
    const float* be2   = (const float*)d_in[10];
    float* out = (float*)d_out;

    char* ws = (char*)d_ws;
    ushort_t* xn     = (ushort_t*)ws;
    ushort_t* yn     = (ushort_t*)(ws + 16777216);
    ushort_t* xb     = (ushort_t*)(ws + 2 * 16777216);
    ushort_t* bt_in  = (ushort_t*)(ws + 3 * 16777216);
    ushort_t* bt_out = bt_in + WELEM;
    ushort_t* W1b    = bt_out + WELEM;
    ushort_t* W2b    = W1b + WELEM;
    // P (2 x 33.5 MB f32) and H (134 MB bf16) share the tail region:
    // P is dead after tt_combine, before ff_g1 writes H. Peak = 188,743,680 B
    // == the ws requirement already proven satisfied in R12.
    float*    P      = (float*)(ws + 54525952);
    ushort_t* Hbuf   = (ushort_t*)(ws + 54525952);

    // 1) weights -> bf16
    convert_weights<<<dim3(768), dim3(256), 0, stream>>>(w_in, w_out, W1, W2,
                                                         bt_in, bt_out, W1b, W2b);
    // 2) LN1
    ln_fast<<<dim3(M_SZ / 4), dim3(256), 0, stream>>>(ent, g1, be1, xn);
    // 3) TT gemm, K-split 2 -> partials (full grid: 256 blocks)
    tt_ks<<<dim3(256), dim3(512), 0, stream>>>(xn, bt_in, bt_out, P);
    // 4) combine + LN2 -> yn, xb
    tt_combine<<<dim3(M_SZ / 4), dim3(256), 0, stream>>>(P, ent, g2, be2, yn, xb);
    // 5) FF1 -> H (1024 blocks)
    ff_g1<<<dim3(1024), dim3(512), 0, stream>>>(yn, W1b, bias1, Hbuf);
    // 6) FF2 + residual -> out (128 blocks)
    ff_g2<<<dim3(128), dim3(512), 0, stream>>>(Hbuf, W2b, bias2, xb, out);
}